// Round 4
// baseline (873.309 us; speedup 1.0000x reference)
//
#include <hip/hip_runtime.h>
#include <math.h>

// kNN (B=1024, C=500000, D=64) + inverse-distance weighting, top-50.
// R4: filter = 512-thr blocks (4 blocks/CU barrier overlap), 64-row staging,
// inline tnorm during staging (tnorm kernel deleted), batched epilogue
// prechecks. select = rank-based top-50 (no serial extraction loop).
// Pipeline: qthresh -> filter_mfma -> select.

#define DELTA_SMOOTH 1e-3f
#define K_NEIGH 50
#define MAXCAP 8192
#define SAMPLE 2048
#define SAMPLE_TARGET 6
#define NBINS 256
#define MARGIN 0.75f       // bf16 dot worst-case error margin (d2 units)
#define MARGIN_Q 26        // select margin in d2q quanta: 2*(0.75+1/16)*16
#define RPB 1024           // table rows per filter block
#define QTILE 512          // queries per filter block (8 waves x 64)
#define SDEPTH 8           // LDS staging slots per (block,query); lambda~3
#define LW 768             // select rescore list size
#define NQ 1024

typedef __attribute__((ext_vector_type(8))) short short8;
typedef __attribute__((ext_vector_type(4))) float f32x4;

__device__ __forceinline__ unsigned f2bf(float f) {
  unsigned u = __float_as_uint(f);
  return ((u + 0x7fffu + ((u >> 16) & 1u)) >> 16) & 0xffffu;
}

// ---------------- Kernel 1: per-query radius from sampled histogram ----------------
// 4 lanes cooperate per row; row norms computed inline (no tnorm dependency).
__global__ __launch_bounds__(256) void qthresh_kernel(
    const float* __restrict__ keys, const float* __restrict__ tk,
    float* __restrict__ thr, float* __restrict__ qnorm, int C) {
  int q = blockIdx.x;
  __shared__ __align__(16) float kq[64];
  __shared__ unsigned hist[NBINS];
  __shared__ float qn_sh;
  __shared__ unsigned wsum[4];
  __shared__ int bstar_sh;
  int tid = threadIdx.x;
  int lane = tid & 63;
  int wid = tid >> 6;
  if (tid < 64) kq[tid] = keys[(size_t)q * 64 + tid];
  hist[tid] = 0u;
  if (tid == 0) bstar_sh = NBINS - 1;
  __syncthreads();
  if (tid < 64) {
    float v = kq[tid];
    float s = v * v;
    #pragma unroll
    for (int off = 32; off > 0; off >>= 1) s += __shfl_down(s, off);
    if (tid == 0) qn_sh = s;
  }
  __syncthreads();
  float qn = qn_sh;
  int kc = lane & 3;
  const float4* kq4 = (const float4*)kq;
  float4 kf[4];
  #pragma unroll
  for (int j = 0; j < 4; ++j) kf[j] = kq4[kc * 4 + j];
  int S = SAMPLE < C ? SAMPLE : C;
  for (int r = wid * (S >> 2) + (lane >> 2); r < (wid + 1) * (S >> 2); r += 16) {
    const float4* trow = (const float4*)(tk + (size_t)r * 64 + kc * 16);
    float a0 = 0.f, a1 = 0.f, sq = 0.f;
    #pragma unroll
    for (int j = 0; j < 4; ++j) {
      float4 tvv = trow[j];
      float4 kv = kf[j];
      a0 += kv.x * tvv.x + kv.y * tvv.y;
      a1 += kv.z * tvv.z + kv.w * tvv.w;
      sq += tvv.x * tvv.x + tvv.y * tvv.y + tvv.z * tvv.z + tvv.w * tvv.w;
    }
    float s = a0 + a1;
    s += __shfl_xor(s, 1); s += __shfl_xor(s, 2);
    sq += __shfl_xor(sq, 1); sq += __shfl_xor(sq, 2);
    if (kc == 0) {
      float d2 = qn + sq - 2.f * s;
      int b = (int)d2;
      b = b < 0 ? 0 : (b > NBINS - 1 ? NBINS - 1 : b);
      atomicAdd(&hist[b], 1u);
    }
  }
  __syncthreads();
  unsigned h = hist[tid];
  unsigned p = h;
  #pragma unroll
  for (int off = 1; off < 64; off <<= 1) {
    unsigned v = __shfl_up(p, off);
    if (lane >= off) p += v;
  }
  if (lane == 63) wsum[wid] = p;
  __syncthreads();
  unsigned add = 0;
  for (int w2 = 0; w2 < wid; ++w2) add += wsum[w2];
  p += add;
  if (p >= (unsigned)SAMPLE_TARGET && p - h < (unsigned)SAMPLE_TARGET) bstar_sh = tid;
  __syncthreads();
  if (tid == 0) {
    thr[q] = (float)(bstar_sh + 1) + MARGIN - qn;
    qnorm[q] = qn;
  }
}

// ---------------- Kernel 2: bf16 MFMA radius filter ----------------
// 512 thr = 8 waves; wave owns 64 queries (4 m-tiles). 64 rows staged/iter
// (fp32->bf16, row norms computed inline during staging). Hits -> LDS staging
// buffer, one global atomic per (block,query) at flush.
// Payload: (d2q13 << 19) | row_idx  (C < 2^19).
__global__ __launch_bounds__(512, 8) void filter_mfma_kernel(
    const float* __restrict__ keys, const float* __restrict__ tk,
    const float* __restrict__ thr, const float* __restrict__ qnorm,
    int* __restrict__ cnt, unsigned* __restrict__ candi, int C, int cap) {
  __shared__ float tnstage[64];                       // row norms, this stage
  __shared__ float thr_lds[QTILE];                    // 2 KB
  __shared__ float qn_lds[QTILE];                     // 2 KB
  __shared__ unsigned scnt[QTILE];                    // 2 KB
  __shared__ unsigned sbuf[QTILE * SDEPTH];           // 16 KB
  __shared__ __align__(16) unsigned char bstage[64 * 128];  // 8 KB

  int tid = threadIdx.x;
  int qt = blockIdx.x & 1;
  int chunk = blockIdx.x >> 1;
  int qbase = qt * QTILE;
  int rstart = chunk * RPB;

  thr_lds[tid] = thr[qbase + tid];
  qn_lds[tid] = qnorm[qbase + tid];
  scnt[tid] = 0u;

  int lane = tid & 63;
  int wq = tid >> 6;       // 0..7
  int l15 = lane & 15;
  int quad = lane >> 4;

  // A fragments: 4 m-tiles; A[m=l15][k=s*32+quad*8+j] (verified R2/R3)
  short8 afrag[4][2];
  #pragma unroll
  for (int mt = 0; mt < 4; ++mt) {
    const float* kp = keys + (size_t)(qbase + wq * 64 + mt * 16 + l15) * 64 + quad * 8;
    #pragma unroll
    for (int s = 0; s < 2; ++s) {
      float4 x = *(const float4*)(kp + s * 32);
      float4 y = *(const float4*)(kp + s * 32 + 4);
      short8 a;
      a[0] = (short)f2bf(x.x); a[1] = (short)f2bf(x.y);
      a[2] = (short)f2bf(x.z); a[3] = (short)f2bf(x.w);
      a[4] = (short)f2bf(y.x); a[5] = (short)f2bf(y.y);
      a[6] = (short)f2bf(y.z); a[7] = (short)f2bf(y.w);
      afrag[mt][s] = a;
    }
  }
  __syncthreads();

  // per-(mt) quad-max threshold precheck (exact thr re-checked in rare path)
  float hq[4];
  #pragma unroll
  for (int mt = 0; mt < 4; ++mt) {
    float h0 = thr_lds[wq * 64 + mt * 16 + quad * 4 + 0];
    float h1 = thr_lds[wq * 64 + mt * 16 + quad * 4 + 1];
    float h2 = thr_lds[wq * 64 + mt * 16 + quad * 4 + 2];
    float h3 = thr_lds[wq * 64 + mt * 16 + quad * 4 + 3];
    hq[mt] = fmaxf(fmaxf(h0, h1), fmaxf(h2, h3));
  }

  // staging: thread -> row srow (0..63), 8-float chunk scol (0..7)
  int srow = tid >> 3;
  int scol = tid & 7;
  unsigned sbyte = (unsigned)(srow * 128 + ((scol ^ (srow & 7)) << 4));

  const int ITERS = RPB / 64;
  int r0 = rstart + srow; if (r0 > C - 1) r0 = C - 1;
  float4 pa = *(const float4*)(tk + (size_t)r0 * 64 + scol * 8);
  float4 pb = *(const float4*)(tk + (size_t)r0 * 64 + scol * 8 + 4);

  f32x4 zero4 = {0.f, 0.f, 0.f, 0.f};

  for (int it = 0; it < ITERS; ++it) {
    // row-norm partial (8 lanes per row) + bf16 pack + b128 LDS write
    float part = pa.x * pa.x + pa.y * pa.y + pa.z * pa.z + pa.w * pa.w
               + pb.x * pb.x + pb.y * pb.y + pb.z * pb.z + pb.w * pb.w;
    part += __shfl_xor(part, 1);
    part += __shfl_xor(part, 2);
    part += __shfl_xor(part, 4);
    if ((tid & 7) == 0) tnstage[srow] = part;
    uint4 u;
    u.x = f2bf(pa.x) | (f2bf(pa.y) << 16);
    u.y = f2bf(pa.z) | (f2bf(pa.w) << 16);
    u.z = f2bf(pb.x) | (f2bf(pb.y) << 16);
    u.w = f2bf(pb.z) | (f2bf(pb.w) << 16);
    *(uint4*)(bstage + sbyte) = u;
    __syncthreads();
    if (it + 1 < ITERS) {
      int rn = rstart + (it + 1) * 64 + srow; if (rn > C - 1) rn = C - 1;
      pa = *(const float4*)(tk + (size_t)rn * 64 + scol * 8);
      pb = *(const float4*)(tk + (size_t)rn * 64 + scol * 8 + 4);
    }
    #pragma unroll
    for (int half = 0; half < 2; ++half) {
      // B fragments: B[k=s*32+quad*8+j][n = half*32 + tt*16 + l15]
      short8 b[2][2];
      #pragma unroll
      for (int tt = 0; tt < 2; ++tt) {
        int nloc = half * 32 + tt * 16 + l15;
        #pragma unroll
        for (int s = 0; s < 2; ++s) {
          int c = s * 4 + quad;
          unsigned addr = (unsigned)(nloc * 128 + ((c ^ (nloc & 7)) << 4));
          b[tt][s] = *(const short8*)(bstage + addr);
        }
      }
      f32x4 acc[4][2];
      #pragma unroll
      for (int mt = 0; mt < 4; ++mt) {
        #pragma unroll
        for (int tt = 0; tt < 2; ++tt) {
          f32x4 a0 = __builtin_amdgcn_mfma_f32_16x16x32_bf16(afrag[mt][0], b[tt][0], zero4, 0, 0, 0);
          acc[mt][tt] = __builtin_amdgcn_mfma_f32_16x16x32_bf16(afrag[mt][1], b[tt][1], a0, 0, 0, 0);
        }
      }
      #pragma unroll
      for (int tt = 0; tt < 2; ++tt) {
        float tn = tnstage[half * 32 + tt * 16 + l15];
        int n = rstart + it * 64 + half * 32 + tt * 16 + l15;
        #pragma unroll
        for (int mt = 0; mt < 4; ++mt) {
          // C/D layout: col(n)=lane&15, row(m)=quad*4+r
          float d0 = fmaf(-2.f, acc[mt][tt][0], tn);
          float d1 = fmaf(-2.f, acc[mt][tt][1], tn);
          float d2 = fmaf(-2.f, acc[mt][tt][2], tn);
          float d3 = fmaf(-2.f, acc[mt][tt][3], tn);
          float mn4 = fminf(fminf(d0, d1), fminf(d2, d3));
          if (mn4 < hq[mt]) {
            float dd[4] = {d0, d1, d2, d3};
            #pragma unroll
            for (int r = 0; r < 4; ++r) {
              int ql = wq * 64 + mt * 16 + quad * 4 + r;
              if (dd[r] < thr_lds[ql] && n < C) {
                float d2f = dd[r] + qn_lds[ql];
                int d2q = (int)(d2f * 16.f);
                d2q = d2q < 0 ? 0 : (d2q > 8191 ? 8191 : d2q);
                unsigned v = ((unsigned)d2q << 19) | (unsigned)n;
                unsigned p = atomicAdd(&scnt[ql], 1u);
                if (p < SDEPTH) {
                  sbuf[ql * SDEPTH + p] = v;
                } else {
                  int g = atomicAdd(&cnt[qbase + ql], 1);
                  if (g < cap) candi[(size_t)(qbase + ql) * cap + g] = v;
                }
              }
            }
          }
        }
      }
    }
    __syncthreads();
  }
  // flush: one global atomic per (block, query)
  int m = (int)scnt[tid];
  if (m > SDEPTH) m = SDEPTH;
  if (m > 0) {
    int base = atomicAdd(&cnt[qbase + tid], m);
    for (int j = 0; j < m; ++j) {
      int g = base + j;
      if (g < cap) candi[(size_t)(qbase + tid) * cap + g] = sbuf[tid * SDEPTH + j];
    }
  }
}

// ---------------- Kernel 3: compact by approx d2, exact rescore, rank-select ----------------
__global__ __launch_bounds__(256) void select_kernel(
    const float* __restrict__ keys, const float* __restrict__ tk,
    const float* __restrict__ tv, const int* __restrict__ cnt,
    const unsigned* __restrict__ candi, float* __restrict__ out, int cap) {
  int q = blockIdx.x;
  __shared__ unsigned hist[NBINS];
  __shared__ unsigned wsum[4];
  __shared__ unsigned minq_sh;
  __shared__ int b50_sh;
  __shared__ int lidx[LW];
  __shared__ unsigned ed2[LW];
  __shared__ int m_sh;
  __shared__ float redw[4], redwv[4];
  int tid = threadIdx.x;
  int lane = tid & 63;
  int wid = tid >> 6;
  int n = cnt[q];
  if (n > cap) n = cap;
  hist[tid] = 0u;
  if (tid == 0) { minq_sh = 0xffffffffu; b50_sh = NBINS - 1; m_sh = 0; }
  __syncthreads();
  const unsigned* cv = candi + (size_t)q * cap;
  // phase A0: min approx-d2 (base for fine histogram)
  unsigned mn = 0xffffffffu;
  for (int i = tid; i < n; i += 256) { unsigned d = cv[i] >> 19; if (d < mn) mn = d; }
  #pragma unroll
  for (int off = 1; off < 64; off <<= 1) { unsigned o = __shfl_xor(mn, off); if (o < mn) mn = o; }
  if (lane == 0) atomicMin(&minq_sh, mn);
  __syncthreads();
  unsigned base = minq_sh;
  // phase A1: fine histogram, bin = 2 quanta (0.125 d2 units)
  for (int i = tid; i < n; i += 256) {
    unsigned d = (cv[i] >> 19) - base;
    unsigned b = d >> 1; if (b > NBINS - 1) b = NBINS - 1;
    atomicAdd(&hist[b], 1u);
  }
  __syncthreads();
  unsigned h = hist[tid];
  unsigned p = h;
  #pragma unroll
  for (int off = 1; off < 64; off <<= 1) {
    unsigned v = __shfl_up(p, off);
    if (lane >= off) p += v;
  }
  if (lane == 63) wsum[wid] = p;
  __syncthreads();
  unsigned add = 0;
  for (int w2 = 0; w2 < wid; ++w2) add += wsum[w2];
  p += add;
  if (p >= (unsigned)K_NEIGH && p - h < (unsigned)K_NEIGH) b50_sh = tid;
  __syncthreads();
  unsigned Tq = base + (((unsigned)(b50_sh + 1)) << 1) + MARGIN_Q;
  // phase B: compact candidates within margin of the 50th-quantile bin
  for (int i = tid; i < n; i += 256) {
    unsigned v = cv[i];
    if ((v >> 19) <= Tq) {
      int p2 = atomicAdd(&m_sh, 1);
      if (p2 < LW) lidx[p2] = (int)(v & 0x7ffffu);
    }
  }
  __syncthreads();
  int m = m_sh; if (m > LW) m = LW;
  // phase C: exact fp32 rescore (wave per candidate, 4x ILP)
  float kqv = keys[(size_t)q * 64 + lane];
  for (int i0 = wid * 4; i0 < m; i0 += 16) {
    int mm = m - i0; if (mm > 4) mm = 4;
    int idx[4]; float t[4];
    for (int u = 0; u < mm; ++u) idx[u] = lidx[i0 + u];
    for (int u = 0; u < mm; ++u) t[u] = tk[(size_t)idx[u] * 64 + lane];
    for (int u = 0; u < mm; ++u) {
      float d = t[u] - kqv;
      float s = d * d;
      #pragma unroll
      for (int off = 1; off < 64; off <<= 1) s += __shfl_xor(s, off);
      if (lane == 0) ed2[i0 + u] = __float_as_uint(s);
    }
  }
  __syncthreads();
  // phase D: rank via all-pairs count; rank<50 contributes (ties by row idx)
  float accw = 0.f, accwv = 0.f;
  for (int i = tid; i < m; i += 256) {
    unsigned long long key = ((unsigned long long)ed2[i] << 19) | (unsigned)lidx[i];
    int rank = 0;
    for (int j = 0; j < m; ++j) {
      unsigned long long kj = ((unsigned long long)ed2[j] << 19) | (unsigned)lidx[j];
      rank += (kj < key) ? 1 : 0;
    }
    if (rank < K_NEIGH) {
      float d2 = __uint_as_float(ed2[i]);
      float w = 1.f / (d2 + DELTA_SMOOTH);
      accw += w;
      accwv += w * tv[lidx[i]];
    }
  }
  #pragma unroll
  for (int off = 1; off < 64; off <<= 1) {
    accw += __shfl_xor(accw, off);
    accwv += __shfl_xor(accwv, off);
  }
  if (lane == 0) { redw[wid] = accw; redwv[wid] = accwv; }
  __syncthreads();
  if (tid == 0) {
    float sw = redw[0] + redw[1] + redw[2] + redw[3];
    float swv = redwv[0] + redwv[1] + redwv[2] + redwv[3];
    out[q] = swv / sw;
  }
}

extern "C" void kernel_launch(void* const* d_in, const int* in_sizes, int n_in,
                              void* d_out, int out_size, void* d_ws, size_t ws_size,
                              hipStream_t stream) {
  const float* keys = (const float*)d_in[0];   // [B,64]
  const float* tk   = (const float*)d_in[1];   // [C,64]
  const float* tv   = (const float*)d_in[2];   // [C]
  float* out = (float*)d_out;
  int B = in_sizes[0] / 64;   // 1024
  int C = in_sizes[2];        // 500000 (< 2^19 for packing)

  char* w = (char*)d_ws;
  float* thr = (float*)w;  w += (size_t)B * 4;
  float* qn  = (float*)w;  w += (size_t)B * 4;
  int*   cnt = (int*)w;    w += (size_t)B * 4;
  size_t used = (size_t)(w - (char*)d_ws);
  size_t avail = ws_size > used ? ws_size - used : 0;
  int cap = (int)(avail / (4ull * (size_t)B));
  if (cap > MAXCAP) cap = MAXCAP;
  if (cap < 1) cap = 1;
  unsigned* candi = (unsigned*)w;

  hipMemsetAsync(cnt, 0, (size_t)B * 4, stream);
  qthresh_kernel<<<B, 256, 0, stream>>>(keys, tk, thr, qn, C);
  int nchunks = (C + RPB - 1) / RPB;
  filter_mfma_kernel<<<nchunks * 2, 512, 0, stream>>>(keys, tk, thr, qn,
                                                      cnt, candi, C, cap);
  select_kernel<<<B, 256, 0, stream>>>(keys, tk, tv, cnt, candi, out, cap);
}

// Round 5
// 450.012 us; speedup vs baseline: 1.9406x; 1.9406x over previous
//
#include <hip/hip_runtime.h>
#include <math.h>

// kNN (B=1024, C=500000, D=64) + inverse-distance weighting, top-50.
// R5: identical to R4 except __launch_bounds__(512, 4) on the filter.
// R4's (512,8) capped VGPRs at 64 -> massive scratch spill (1.8 GB fetch).
// (512,4) = 128-VGPR cap fits the ~100-VGPR working set (afrag 32 + acc 32
// + b 16 + prefetch/addr ~20) with 16 waves/CU = 2 barrier groups/CU.
// Pipeline: qthresh -> filter_mfma -> select.

#define DELTA_SMOOTH 1e-3f
#define K_NEIGH 50
#define MAXCAP 8192
#define SAMPLE 2048
#define SAMPLE_TARGET 6
#define NBINS 256
#define MARGIN 0.75f       // bf16 dot worst-case error margin (d2 units)
#define MARGIN_Q 26        // select margin in d2q quanta: 2*(0.75+1/16)*16
#define RPB 1024           // table rows per filter block
#define QTILE 512          // queries per filter block (8 waves x 64)
#define SDEPTH 8           // LDS staging slots per (block,query); lambda~3
#define LW 768             // select rescore list size
#define NQ 1024

typedef __attribute__((ext_vector_type(8))) short short8;
typedef __attribute__((ext_vector_type(4))) float f32x4;

__device__ __forceinline__ unsigned f2bf(float f) {
  unsigned u = __float_as_uint(f);
  return ((u + 0x7fffu + ((u >> 16) & 1u)) >> 16) & 0xffffu;
}

// ---------------- Kernel 1: per-query radius from sampled histogram ----------------
__global__ __launch_bounds__(256) void qthresh_kernel(
    const float* __restrict__ keys, const float* __restrict__ tk,
    float* __restrict__ thr, float* __restrict__ qnorm, int C) {
  int q = blockIdx.x;
  __shared__ __align__(16) float kq[64];
  __shared__ unsigned hist[NBINS];
  __shared__ float qn_sh;
  __shared__ unsigned wsum[4];
  __shared__ int bstar_sh;
  int tid = threadIdx.x;
  int lane = tid & 63;
  int wid = tid >> 6;
  if (tid < 64) kq[tid] = keys[(size_t)q * 64 + tid];
  hist[tid] = 0u;
  if (tid == 0) bstar_sh = NBINS - 1;
  __syncthreads();
  if (tid < 64) {
    float v = kq[tid];
    float s = v * v;
    #pragma unroll
    for (int off = 32; off > 0; off >>= 1) s += __shfl_down(s, off);
    if (tid == 0) qn_sh = s;
  }
  __syncthreads();
  float qn = qn_sh;
  int kc = lane & 3;
  const float4* kq4 = (const float4*)kq;
  float4 kf[4];
  #pragma unroll
  for (int j = 0; j < 4; ++j) kf[j] = kq4[kc * 4 + j];
  int S = SAMPLE < C ? SAMPLE : C;
  for (int r = wid * (S >> 2) + (lane >> 2); r < (wid + 1) * (S >> 2); r += 16) {
    const float4* trow = (const float4*)(tk + (size_t)r * 64 + kc * 16);
    float a0 = 0.f, a1 = 0.f, sq = 0.f;
    #pragma unroll
    for (int j = 0; j < 4; ++j) {
      float4 tvv = trow[j];
      float4 kv = kf[j];
      a0 += kv.x * tvv.x + kv.y * tvv.y;
      a1 += kv.z * tvv.z + kv.w * tvv.w;
      sq += tvv.x * tvv.x + tvv.y * tvv.y + tvv.z * tvv.z + tvv.w * tvv.w;
    }
    float s = a0 + a1;
    s += __shfl_xor(s, 1); s += __shfl_xor(s, 2);
    sq += __shfl_xor(sq, 1); sq += __shfl_xor(sq, 2);
    if (kc == 0) {
      float d2 = qn + sq - 2.f * s;
      int b = (int)d2;
      b = b < 0 ? 0 : (b > NBINS - 1 ? NBINS - 1 : b);
      atomicAdd(&hist[b], 1u);
    }
  }
  __syncthreads();
  unsigned h = hist[tid];
  unsigned p = h;
  #pragma unroll
  for (int off = 1; off < 64; off <<= 1) {
    unsigned v = __shfl_up(p, off);
    if (lane >= off) p += v;
  }
  if (lane == 63) wsum[wid] = p;
  __syncthreads();
  unsigned add = 0;
  for (int w2 = 0; w2 < wid; ++w2) add += wsum[w2];
  p += add;
  if (p >= (unsigned)SAMPLE_TARGET && p - h < (unsigned)SAMPLE_TARGET) bstar_sh = tid;
  __syncthreads();
  if (tid == 0) {
    thr[q] = (float)(bstar_sh + 1) + MARGIN - qn;
    qnorm[q] = qn;
  }
}

// ---------------- Kernel 2: bf16 MFMA radius filter ----------------
// 512 thr = 8 waves; wave owns 64 queries (4 m-tiles). 64 rows staged/iter
// (fp32->bf16, row norms computed inline during staging). Hits -> LDS staging
// buffer, one global atomic per (block,query) at flush.
// Payload: (d2q13 << 19) | row_idx  (C < 2^19).
// launch_bounds (512,4): 128-VGPR cap, NO SPILL (R4's (512,8) spilled).
__global__ __launch_bounds__(512, 4) void filter_mfma_kernel(
    const float* __restrict__ keys, const float* __restrict__ tk,
    const float* __restrict__ thr, const float* __restrict__ qnorm,
    int* __restrict__ cnt, unsigned* __restrict__ candi, int C, int cap) {
  __shared__ float tnstage[64];                       // row norms, this stage
  __shared__ float thr_lds[QTILE];                    // 2 KB
  __shared__ float qn_lds[QTILE];                     // 2 KB
  __shared__ unsigned scnt[QTILE];                    // 2 KB
  __shared__ unsigned sbuf[QTILE * SDEPTH];           // 16 KB
  __shared__ __align__(16) unsigned char bstage[64 * 128];  // 8 KB

  int tid = threadIdx.x;
  int qt = blockIdx.x & 1;
  int chunk = blockIdx.x >> 1;
  int qbase = qt * QTILE;
  int rstart = chunk * RPB;

  thr_lds[tid] = thr[qbase + tid];
  qn_lds[tid] = qnorm[qbase + tid];
  scnt[tid] = 0u;

  int lane = tid & 63;
  int wq = tid >> 6;       // 0..7
  int l15 = lane & 15;
  int quad = lane >> 4;

  // A fragments: 4 m-tiles; A[m=l15][k=s*32+quad*8+j] (verified R2/R3)
  short8 afrag[4][2];
  #pragma unroll
  for (int mt = 0; mt < 4; ++mt) {
    const float* kp = keys + (size_t)(qbase + wq * 64 + mt * 16 + l15) * 64 + quad * 8;
    #pragma unroll
    for (int s = 0; s < 2; ++s) {
      float4 x = *(const float4*)(kp + s * 32);
      float4 y = *(const float4*)(kp + s * 32 + 4);
      short8 a;
      a[0] = (short)f2bf(x.x); a[1] = (short)f2bf(x.y);
      a[2] = (short)f2bf(x.z); a[3] = (short)f2bf(x.w);
      a[4] = (short)f2bf(y.x); a[5] = (short)f2bf(y.y);
      a[6] = (short)f2bf(y.z); a[7] = (short)f2bf(y.w);
      afrag[mt][s] = a;
    }
  }
  __syncthreads();

  // per-(mt) quad-max threshold precheck (exact thr re-checked in rare path)
  float hq[4];
  #pragma unroll
  for (int mt = 0; mt < 4; ++mt) {
    float h0 = thr_lds[wq * 64 + mt * 16 + quad * 4 + 0];
    float h1 = thr_lds[wq * 64 + mt * 16 + quad * 4 + 1];
    float h2 = thr_lds[wq * 64 + mt * 16 + quad * 4 + 2];
    float h3 = thr_lds[wq * 64 + mt * 16 + quad * 4 + 3];
    hq[mt] = fmaxf(fmaxf(h0, h1), fmaxf(h2, h3));
  }

  // staging: thread -> row srow (0..63), 8-float chunk scol (0..7)
  int srow = tid >> 3;
  int scol = tid & 7;
  unsigned sbyte = (unsigned)(srow * 128 + ((scol ^ (srow & 7)) << 4));

  const int ITERS = RPB / 64;
  int r0 = rstart + srow; if (r0 > C - 1) r0 = C - 1;
  float4 pa = *(const float4*)(tk + (size_t)r0 * 64 + scol * 8);
  float4 pb = *(const float4*)(tk + (size_t)r0 * 64 + scol * 8 + 4);

  f32x4 zero4 = {0.f, 0.f, 0.f, 0.f};

  for (int it = 0; it < ITERS; ++it) {
    // row-norm partial (8 lanes per row) + bf16 pack + b128 LDS write
    float part = pa.x * pa.x + pa.y * pa.y + pa.z * pa.z + pa.w * pa.w
               + pb.x * pb.x + pb.y * pb.y + pb.z * pb.z + pb.w * pb.w;
    part += __shfl_xor(part, 1);
    part += __shfl_xor(part, 2);
    part += __shfl_xor(part, 4);
    if ((tid & 7) == 0) tnstage[srow] = part;
    uint4 u;
    u.x = f2bf(pa.x) | (f2bf(pa.y) << 16);
    u.y = f2bf(pa.z) | (f2bf(pa.w) << 16);
    u.z = f2bf(pb.x) | (f2bf(pb.y) << 16);
    u.w = f2bf(pb.z) | (f2bf(pb.w) << 16);
    *(uint4*)(bstage + sbyte) = u;
    __syncthreads();
    if (it + 1 < ITERS) {
      int rn = rstart + (it + 1) * 64 + srow; if (rn > C - 1) rn = C - 1;
      pa = *(const float4*)(tk + (size_t)rn * 64 + scol * 8);
      pb = *(const float4*)(tk + (size_t)rn * 64 + scol * 8 + 4);
    }
    #pragma unroll
    for (int half = 0; half < 2; ++half) {
      // B fragments: B[k=s*32+quad*8+j][n = half*32 + tt*16 + l15]
      short8 b[2][2];
      #pragma unroll
      for (int tt = 0; tt < 2; ++tt) {
        int nloc = half * 32 + tt * 16 + l15;
        #pragma unroll
        for (int s = 0; s < 2; ++s) {
          int c = s * 4 + quad;
          unsigned addr = (unsigned)(nloc * 128 + ((c ^ (nloc & 7)) << 4));
          b[tt][s] = *(const short8*)(bstage + addr);
        }
      }
      f32x4 acc[4][2];
      #pragma unroll
      for (int mt = 0; mt < 4; ++mt) {
        #pragma unroll
        for (int tt = 0; tt < 2; ++tt) {
          f32x4 a0 = __builtin_amdgcn_mfma_f32_16x16x32_bf16(afrag[mt][0], b[tt][0], zero4, 0, 0, 0);
          acc[mt][tt] = __builtin_amdgcn_mfma_f32_16x16x32_bf16(afrag[mt][1], b[tt][1], a0, 0, 0, 0);
        }
      }
      #pragma unroll
      for (int tt = 0; tt < 2; ++tt) {
        float tn = tnstage[half * 32 + tt * 16 + l15];
        int n = rstart + it * 64 + half * 32 + tt * 16 + l15;
        #pragma unroll
        for (int mt = 0; mt < 4; ++mt) {
          // C/D layout: col(n)=lane&15, row(m)=quad*4+r
          float d0 = fmaf(-2.f, acc[mt][tt][0], tn);
          float d1 = fmaf(-2.f, acc[mt][tt][1], tn);
          float d2 = fmaf(-2.f, acc[mt][tt][2], tn);
          float d3 = fmaf(-2.f, acc[mt][tt][3], tn);
          float mn4 = fminf(fminf(d0, d1), fminf(d2, d3));
          if (mn4 < hq[mt]) {
            float dd[4] = {d0, d1, d2, d3};
            #pragma unroll
            for (int r = 0; r < 4; ++r) {
              int ql = wq * 64 + mt * 16 + quad * 4 + r;
              if (dd[r] < thr_lds[ql] && n < C) {
                float d2f = dd[r] + qn_lds[ql];
                int d2q = (int)(d2f * 16.f);
                d2q = d2q < 0 ? 0 : (d2q > 8191 ? 8191 : d2q);
                unsigned v = ((unsigned)d2q << 19) | (unsigned)n;
                unsigned p = atomicAdd(&scnt[ql], 1u);
                if (p < SDEPTH) {
                  sbuf[ql * SDEPTH + p] = v;
                } else {
                  int g = atomicAdd(&cnt[qbase + ql], 1);
                  if (g < cap) candi[(size_t)(qbase + ql) * cap + g] = v;
                }
              }
            }
          }
        }
      }
    }
    __syncthreads();
  }
  // flush: one global atomic per (block, query)
  int m = (int)scnt[tid];
  if (m > SDEPTH) m = SDEPTH;
  if (m > 0) {
    int base = atomicAdd(&cnt[qbase + tid], m);
    for (int j = 0; j < m; ++j) {
      int g = base + j;
      if (g < cap) candi[(size_t)(qbase + tid) * cap + g] = sbuf[tid * SDEPTH + j];
    }
  }
}

// ---------------- Kernel 3: compact by approx d2, exact rescore, rank-select ----------------
__global__ __launch_bounds__(256) void select_kernel(
    const float* __restrict__ keys, const float* __restrict__ tk,
    const float* __restrict__ tv, const int* __restrict__ cnt,
    const unsigned* __restrict__ candi, float* __restrict__ out, int cap) {
  int q = blockIdx.x;
  __shared__ unsigned hist[NBINS];
  __shared__ unsigned wsum[4];
  __shared__ unsigned minq_sh;
  __shared__ int b50_sh;
  __shared__ int lidx[LW];
  __shared__ unsigned ed2[LW];
  __shared__ int m_sh;
  __shared__ float redw[4], redwv[4];
  int tid = threadIdx.x;
  int lane = tid & 63;
  int wid = tid >> 6;
  int n = cnt[q];
  if (n > cap) n = cap;
  hist[tid] = 0u;
  if (tid == 0) { minq_sh = 0xffffffffu; b50_sh = NBINS - 1; m_sh = 0; }
  __syncthreads();
  const unsigned* cv = candi + (size_t)q * cap;
  // phase A0: min approx-d2 (base for fine histogram)
  unsigned mn = 0xffffffffu;
  for (int i = tid; i < n; i += 256) { unsigned d = cv[i] >> 19; if (d < mn) mn = d; }
  #pragma unroll
  for (int off = 1; off < 64; off <<= 1) { unsigned o = __shfl_xor(mn, off); if (o < mn) mn = o; }
  if (lane == 0) atomicMin(&minq_sh, mn);
  __syncthreads();
  unsigned base = minq_sh;
  // phase A1: fine histogram, bin = 2 quanta (0.125 d2 units)
  for (int i = tid; i < n; i += 256) {
    unsigned d = (cv[i] >> 19) - base;
    unsigned b = d >> 1; if (b > NBINS - 1) b = NBINS - 1;
    atomicAdd(&hist[b], 1u);
  }
  __syncthreads();
  unsigned h = hist[tid];
  unsigned p = h;
  #pragma unroll
  for (int off = 1; off < 64; off <<= 1) {
    unsigned v = __shfl_up(p, off);
    if (lane >= off) p += v;
  }
  if (lane == 63) wsum[wid] = p;
  __syncthreads();
  unsigned add = 0;
  for (int w2 = 0; w2 < wid; ++w2) add += wsum[w2];
  p += add;
  if (p >= (unsigned)K_NEIGH && p - h < (unsigned)K_NEIGH) b50_sh = tid;
  __syncthreads();
  unsigned Tq = base + (((unsigned)(b50_sh + 1)) << 1) + MARGIN_Q;
  // phase B: compact candidates within margin of the 50th-quantile bin
  for (int i = tid; i < n; i += 256) {
    unsigned v = cv[i];
    if ((v >> 19) <= Tq) {
      int p2 = atomicAdd(&m_sh, 1);
      if (p2 < LW) lidx[p2] = (int)(v & 0x7ffffu);
    }
  }
  __syncthreads();
  int m = m_sh; if (m > LW) m = LW;
  // phase C: exact fp32 rescore (wave per candidate, 4x ILP)
  float kqv = keys[(size_t)q * 64 + lane];
  for (int i0 = wid * 4; i0 < m; i0 += 16) {
    int mm = m - i0; if (mm > 4) mm = 4;
    int idx[4]; float t[4];
    for (int u = 0; u < mm; ++u) idx[u] = lidx[i0 + u];
    for (int u = 0; u < mm; ++u) t[u] = tk[(size_t)idx[u] * 64 + lane];
    for (int u = 0; u < mm; ++u) {
      float d = t[u] - kqv;
      float s = d * d;
      #pragma unroll
      for (int off = 1; off < 64; off <<= 1) s += __shfl_xor(s, off);
      if (lane == 0) ed2[i0 + u] = __float_as_uint(s);
    }
  }
  __syncthreads();
  // phase D: rank via all-pairs count; rank<50 contributes (ties by row idx)
  float accw = 0.f, accwv = 0.f;
  for (int i = tid; i < m; i += 256) {
    unsigned long long key = ((unsigned long long)ed2[i] << 19) | (unsigned)lidx[i];
    int rank = 0;
    for (int j = 0; j < m; ++j) {
      unsigned long long kj = ((unsigned long long)ed2[j] << 19) | (unsigned)lidx[j];
      rank += (kj < key) ? 1 : 0;
    }
    if (rank < K_NEIGH) {
      float d2 = __uint_as_float(ed2[i]);
      float w = 1.f / (d2 + DELTA_SMOOTH);
      accw += w;
      accwv += w * tv[lidx[i]];
    }
  }
  #pragma unroll
  for (int off = 1; off < 64; off <<= 1) {
    accw += __shfl_xor(accw, off);
    accwv += __shfl_xor(accwv, off);
  }
  if (lane == 0) { redw[wid] = accw; redwv[wid] = accwv; }
  __syncthreads();
  if (tid == 0) {
    float sw = redw[0] + redw[1] + redw[2] + redw[3];
    float swv = redwv[0] + redwv[1] + redwv[2] + redwv[3];
    out[q] = swv / sw;
  }
}

extern "C" void kernel_launch(void* const* d_in, const int* in_sizes, int n_in,
                              void* d_out, int out_size, void* d_ws, size_t ws_size,
                              hipStream_t stream) {
  const float* keys = (const float*)d_in[0];   // [B,64]
  const float* tk   = (const float*)d_in[1];   // [C,64]
  const float* tv   = (const float*)d_in[2];   // [C]
  float* out = (float*)d_out;
  int B = in_sizes[0] / 64;   // 1024
  int C = in_sizes[2];        // 500000 (< 2^19 for packing)

  char* w = (char*)d_ws;
  float* thr = (float*)w;  w += (size_t)B * 4;
  float* qn  = (float*)w;  w += (size_t)B * 4;
  int*   cnt = (int*)w;    w += (size_t)B * 4;
  size_t used = (size_t)(w - (char*)d_ws);
  size_t avail = ws_size > used ? ws_size - used : 0;
  int cap = (int)(avail / (4ull * (size_t)B));
  if (cap > MAXCAP) cap = MAXCAP;
  if (cap < 1) cap = 1;
  unsigned* candi = (unsigned*)w;

  hipMemsetAsync(cnt, 0, (size_t)B * 4, stream);
  qthresh_kernel<<<B, 256, 0, stream>>>(keys, tk, thr, qn, C);
  int nchunks = (C + RPB - 1) / RPB;
  filter_mfma_kernel<<<nchunks * 2, 512, 0, stream>>>(keys, tk, thr, qn,
                                                      cnt, candi, C, cap);
  select_kernel<<<B, 256, 0, stream>>>(keys, tk, tv, cnt, candi, out, cap);
}